// Round 11
// baseline (647.985 us; speedup 1.0000x reference)
//
#include <hip/hip_runtime.h>

#define V 16000
#define E 256
#define H 512
#define HP 516     // padded LDS h row stride (4-float pad: bank groups 4r)
#define BB 8       // batch rows
#define T 12       // lenseq
#define NB 250     // persistent blocks: 250*64 == 16000 exactly (1 block/CU)
#define NBS 256    // pq stride (padded)
#define TPB 1024   // 16 waves/block
#define CPB 64     // vocab cols per block: 64*4B = 256B row slice, LINE-ALIGNED
#define BBH (BB * H)
#define AGENT __HIP_MEMORY_SCOPE_AGENT

typedef float vfloat4 __attribute__((ext_vector_type(4)));
typedef unsigned long long u64;

// Greedy degeneracy verified (R3). Persistent kernel since R4. w_out in LDS
// since R9. Established: (i) WRITE_SIZE amplification = red herring. (ii)
// Cross-block data via cache-bypassing relaxed atomics; R14/R18 tree barrier
// is the proven sync structure (R15 flat -65us, R16 fused+acquire -690us,
// R17 plain-stores -30us, R19 relay+cached-pq -33us). R18 op-shaping = best
// (483us). R20 (this round): keep R18 verbatim EXCEPT delete barB. Phase C
// synchronizes on the DATA: pq records are 16B {sum,max,idx,tag}; producer
// writes payload (8B relaxed) then {idx,tag} (8B RELEASE) -> tag-confirmed
// snapshot read is safe (R19 validated mechanics). kinit zeroes pq each
// dispatch (same-stream order => re-poison-safe); tag = t+1, no salt.
// Each C-lane polls only ITS 4 records (bypass RELAXED + s_sleep) ->
// point-to-point dataflow replaces the global fan-in/fan-out. Rotation
// (hbuf[T+1], pq[T]) makes one-step skew hazard-free; barA (producer-only,
// proven) remains the only grid barrier.

// LDS layout (floats)
constexpr int W_FL   = CPB * 512;            // 32768  swizzled w slice (128KB)
constexpr int SH_OFF = W_FL;                 // s_h   [8][516]
constexpr int SP_OFF = SH_OFF + BB * HP;     // s_part 64*48 (A) / s_e [8][65] (B/C)
constexpr int RS_OFF = SP_OFF + 64 * 48;     // s_rsum [16][8] (+ phase-A h gather)
constexpr int RV_OFF = RS_OFF + 128;         // s_rval
constexpr int RI_OFF = RV_OFF + 128;         // s_ridx (int)
constexpr int SS_OFF = RI_OFF + 128;         // s_S   [8]
constexpr int XN_OFF = SS_OFF + 8;           // s_Xn  [8] (int)
constexpr int X_OFF  = XN_OFF + 8;           // s_X   [8] (int)
constexpr int SMEM_FL = X_OFF + 8;
constexpr size_t SMEM_BYTES = (size_t)SMEM_FL * 4;   // 161,504 B < 160 KiB

// cnt line map (16 ints per line):
//   line  63    : epochA word (h-ready publish)
//   lines 64..79: bar1 leaf counters (16 x 4 = 64 producer arrivals)
constexpr int CNT_LINES = 84;

__device__ __forceinline__ float dot4(float4 a, float4 b) {
    return a.x * b.x + a.y * b.y + a.z * b.z + a.w * b.w;
}

__global__ __launch_bounds__(256) void kinit(const float* __restrict__ hidden,
                                             float* __restrict__ hbuf,
                                             int* __restrict__ cnt,
                                             vfloat4* __restrict__ pq) {
    int idx = blockIdx.x * 256 + threadIdx.x;
    if (idx < BBH) hbuf[idx] = hidden[idx];
    if (idx < CNT_LINES * 16) cnt[idx] = 0;
    for (int i = idx; i < T * 8 * NBS; i += 16 * 256)
        pq[i] = (vfloat4){0.f, 0.f, 0.f, 0.f};   // tag=0: re-poison each dispatch
}

// bar1 (R18 verbatim): producer-only arrivals (blocks 0..63 on 16 leaf
// lines) -> block0 publishes epochA -> everyone polls ONE word RELAXED.
__device__ __forceinline__ void barA(int* __restrict__ cnt, int ep) {
    __syncthreads();
    if (blockIdx.x < 64 && threadIdx.x == 0)
        __hip_atomic_fetch_add(&cnt[(64 + (blockIdx.x >> 2)) * 16], 1,
                               __ATOMIC_RELEASE, AGENT);
    if (blockIdx.x == 0) {
        if (threadIdx.x < 16) {
            while (__hip_atomic_load(&cnt[(64 + threadIdx.x) * 16],
                                     __ATOMIC_RELAXED, AGENT) < 4 * ep)
                __builtin_amdgcn_s_sleep(1);
        }
        __syncthreads();
        if (threadIdx.x == 0)
            __hip_atomic_store(&cnt[63 * 16], ep, __ATOMIC_RELAXED, AGENT);
    } else {
        if (threadIdx.x == 0) {
            while (__hip_atomic_load(&cnt[63 * 16], __ATOMIC_RELAXED, AGENT) < ep)
                __builtin_amdgcn_s_sleep(1);
        }
    }
    __builtin_amdgcn_fence(__ATOMIC_ACQUIRE, "workgroup");
    __syncthreads();
}

__global__ __launch_bounds__(TPB, 4) void kmain(
    const float* __restrict__ emb_tab,
    const float* __restrict__ w_ih,
    const float* __restrict__ w_hh,
    const float* __restrict__ b_ih,
    const float* __restrict__ b_hh,
    const float* __restrict__ w_out,
    const float* __restrict__ b_out,
    float* __restrict__ hbuf,   // [T+1][BB*H] rotated h buffers
    vfloat4* __restrict__ pq,   // [T][8][NBS] {sum,max,idxbits,tagbits}
    int* __restrict__ cnt,
    float* __restrict__ out)
{
    extern __shared__ float smem[];
    float* w_lds  = smem;
    float* s_h    = smem + SH_OFF;
    float* s_part = smem + SP_OFF;
    float* s_e    = smem + SP_OFF;          // alias: phase-B/C e buffer [8][65]
    float* s_rsum = smem + RS_OFF;
    float* s_rval = smem + RV_OFF;
    int*   s_ridx = (int*)(smem + RI_OFF);
    float* s_S    = smem + SS_OFF;
    int*   s_Xn   = (int*)(smem + XN_OFF);
    int*   s_X    = (int*)(smem + X_OFF);

    const int blk = blockIdx.x, tid = threadIdx.x;

    // ---- stage this block's w_out slice into LDS, swizzled, ONCE ----------
    // layout: w_lds[col*512 + (k ^ ((col&7)<<2) ^ (((k>>5)&7)<<2))]
    for (int i = tid; i < CPB * 128; i += TPB) {
        int col = i >> 7;
        int q4  = (i & 127) << 2;
        int vv  = blk * CPB + col;          // always < V (250*64 == 16000)
        float4 w4 = *(const float4*)(w_out + (size_t)vv * H + q4);
        int sw = q4 ^ ((col & 7) << 2) ^ (((q4 >> 5) & 7) << 2);
        *(float4*)(w_lds + col * 512 + sw) = w4;
    }
    if (tid < BB) s_X[tid] = 1;             // SOS
    __syncthreads();

    // ---- phase-B lane mapping: rh=bits0-1, kq=bits2-5 (16 K-chunks of 32)
    // wave: rowhalf=bit0, col-slot cs=bits1-4; per pass p: col = p*8 + cs
    const int lane = tid & 63;
    const int wv   = tid >> 6;              // 0..15
    const int rh   = lane & 3;
    const int kq   = (lane >> 2) & 15;      // K chunk (32 floats)
    const int rowhalf = wv & 1;
    const int cs   = wv >> 1;               // 0..7
    const int r    = rowhalf * 4 + rh;      // 0..7
    const int xw   = (cs ^ (kq & 7)) << 2;  // w swizzle for this (col-slot,kq)
    const int hswz = (kq & 7) << 2;         // h swizzle for this kq

    // b_out is step-invariant: hoist the 8 per-pass values into VGPRs once
    float bo[8];
#pragma unroll
    for (int p = 0; p < 8; p++) bo[p] = b_out[blk * CPB + p * 8 + cs];

    for (int t = 0; t < T; t++) {
        const float* h_cur = hbuf + (size_t)t * BBH;        // rotated
        float*       h_nxt = hbuf + (size_t)(t + 1) * BBH;  // write-once

        // ---------------- phase A: GRU cell (blocks 0..63) ----------------
        if (blk < 64) {                     // stage h_cur (8B bypass loads)
            int hr = tid >> 7, k4 = (tid & 127) << 2;
            const u64* p = (const u64*)(h_cur + hr * H + k4);
            union { u64 u; float f[2]; } c0, c1;
            c0.u = __hip_atomic_load(p,     __ATOMIC_RELAXED, AGENT);
            c1.u = __hip_atomic_load(p + 1, __ATOMIC_RELAXED, AGENT);
            *(float4*)(s_h + hr * HP + k4) =
                make_float4(c0.f[0], c0.f[1], c1.f[0], c1.f[1]);
        }
        __syncthreads();
        if (blk < 64 && tid < 512) {
            const int jl = tid >> 6;        // 0..7
            const int ar = (tid >> 3) & 7;  // row
            const int kq8 = tid & 7;        // K split 8
            const int j  = blk * 8 + jl;
            const int pair = jl * 8 + ar;
            float gir = 0.f, giz = 0.f, gin = 0.f, ghr = 0.f, ghz = 0.f, ghn = 0.f;
            {
                const float* erow = emb_tab + (size_t)s_X[ar] * E;
                const float* w0 = w_ih + (size_t)j * E;
                const float* w1 = w0 + (size_t)H * E;
                const float* w2 = w1 + (size_t)H * E;
                const int k0 = kq8 * (E / 8);
                for (int k = 0; k < E / 8; k += 4) {
                    float4 ev = *(const float4*)(erow + k0 + k);
                    gir += dot4(*(const float4*)(w0 + k0 + k), ev);
                    giz += dot4(*(const float4*)(w1 + k0 + k), ev);
                    gin += dot4(*(const float4*)(w2 + k0 + k), ev);
                }
            }
            {
                const float* hrow = s_h + ar * HP;
                const float* w0 = w_hh + (size_t)j * H;
                const float* w1 = w0 + (size_t)H * H;
                const float* w2 = w1 + (size_t)H * H;
                const int k0 = kq8 * (H / 8);
                for (int k = 0; k < H / 8; k += 4) {
                    float4 hv = *(const float4*)(hrow + k0 + k);
                    ghr += dot4(*(const float4*)(w0 + k0 + k), hv);
                    ghz += dot4(*(const float4*)(w1 + k0 + k), hv);
                    ghn += dot4(*(const float4*)(w2 + k0 + k), hv);
                }
            }
            float* sp = s_part + pair * 48;
            sp[0 * 8 + kq8] = gir; sp[1 * 8 + kq8] = giz; sp[2 * 8 + kq8] = gin;
            sp[3 * 8 + kq8] = ghr; sp[4 * 8 + kq8] = ghz; sp[5 * 8 + kq8] = ghn;
        }
        __syncthreads();
        if (blk < 64 && tid < 512 && (tid & 7) == 0) {
            const int pair = (tid >> 6) * 8 + ((tid >> 3) & 7);
            const int jl = pair >> 3, ar = pair & 7;
            const int j  = blk * 8 + jl;
            const float* sp2 = s_part + pair * 48;
            float G[6];
#pragma unroll
            for (int gg = 0; gg < 6; gg++) {
                float s = 0.f;
#pragma unroll
                for (int q = 0; q < 8; q++) s += sp2[gg * 8 + q];
                G[gg] = s;
            }
            float ir  = G[0] + b_ih[j],         hr_ = G[3] + b_hh[j];
            float iz  = G[1] + b_ih[H + j],     hz  = G[4] + b_hh[H + j];
            float inn = G[2] + b_ih[2 * H + j], hn  = G[5] + b_hh[2 * H + j];
            float rg = 1.f / (1.f + __expf(-(ir + hr_)));
            float zg = 1.f / (1.f + __expf(-(iz + hz)));
            float ng = tanhf(inn + rg * hn);
            float ho = s_h[ar * HP + j];
            int xr = s_X[ar];
            bool dn = (xr == 0) || (xr == 2);
            float hv = dn ? ho : ((1.f - zg) * ng + zg * ho);
            s_rsum[ar * 8 + jl] = hv;       // gather for packed store
        }
        __syncthreads();
        if (blk < 64 && tid < 32) {         // 32 coalesced 8B bypass stores
            int ar = tid >> 2, q2 = (tid & 3) << 1;
            union { float f[2]; u64 u; } pk;
            pk.f[0] = s_rsum[ar * 8 + q2];
            pk.f[1] = s_rsum[ar * 8 + q2 + 1];
            __hip_atomic_store((u64*)(h_nxt + (size_t)ar * H + blk * 8 + q2),
                               pk.u, __ATOMIC_RELAXED, AGENT);
        }
        barA(cnt, t + 1);

        // -------- phase B: logits from LDS-resident w ----------------------
        {   // stage h_nxt, kq-swizzled (8B bypass loads)
            int hr = tid >> 7, k4 = (tid & 127) << 2;
            const u64* p = (const u64*)(h_nxt + hr * H + k4);
            union { u64 u; float f[2]; } c0, c1;
            c0.u = __hip_atomic_load(p,     __ATOMIC_RELAXED, AGENT);
            c1.u = __hip_atomic_load(p + 1, __ATOMIC_RELAXED, AGENT);
            int sw = k4 ^ (((k4 >> 5) & 7) << 2);
            *(float4*)(s_h + hr * HP + sw) =
                make_float4(c0.f[0], c0.f[1], c1.f[0], c1.f[1]);
        }
        __syncthreads();
        {
            // h chunk -> 32 VGPRs, read ONCE per step
            float4 hreg[8];
            const float* hb = s_h + r * HP + kq * 32;
#pragma unroll
            for (int i = 0; i < 8; i++)
                hreg[i] = *(const float4*)(hb + ((4 * i) ^ hswz));

            float s_acc = 0.f, bv = -1.f; int bi = 0x7fffffff;
#pragma unroll
            for (int p = 0; p < 8; p++) {
                const int col = p * 8 + cs;
                const int vv  = blk * CPB + col;
                const float* wb = w_lds + col * 512 + kq * 32;
                float acc = 0.f;
#pragma unroll
                for (int i = 0; i < 8; i++) {
                    float4 w4 = *(const float4*)(wb + ((4 * i) ^ xw));
                    acc += dot4(w4, hreg[i]);
                }
                // full-K sum across the 16 kq lanes (bits 2-5); butterfly is
                // commutative-add -> bitwise identical on every lane
                acc += __shfl_xor(acc, 4, 64);
                acc += __shfl_xor(acc, 8, 64);
                acc += __shfl_xor(acc, 16, 64);
                acc += __shfl_xor(acc, 32, 64);
                float ee = __expf(acc + bo[p]);
                if (kq == 0) s_e[r * 65 + col] = ee;  // stash for phase-C write
                s_acc += ee;
                if (ee > bv) { bv = ee; bi = vv; }  // earlier pass = smaller v
            }
            if (kq == 0) {                  // designated: real per-r results
                s_rsum[wv * 8 + r] = s_acc;
                s_rval[wv * 8 + r] = bv;
                s_ridx[wv * 8 + r] = bi;
            } else if (kq == 1) {           // neutral fill for other row-half
                int ro = (1 - rowhalf) * 4 + rh;
                s_rsum[wv * 8 + ro] = 0.f;
                s_rval[wv * 8 + ro] = -1.f;
                s_ridx[wv * 8 + ro] = 0x7fffffff;
            }
        }
        __syncthreads();
        if (tid < 64) {                     // reduce 16 waves -> per-row, store
            float s  = s_rsum[tid] + s_rsum[tid + 64];
            float av = s_rval[tid], bv2 = s_rval[tid + 64];
            int   ai = s_ridx[tid], bi2 = s_ridx[tid + 64];
            float bv = av; int bi = ai;
            if (bv2 > bv || (bv2 == bv && bi2 < bi)) { bv = bv2; bi = bi2; }
#pragma unroll
            for (int m = 8; m <= 32; m <<= 1) {
                s += __shfl_xor(s, m, 64);
                float ov = __shfl_xor(bv, m, 64);
                int   oi = __shfl_xor(bi, m, 64);
                if (ov > bv || (ov == bv && oi < bi)) { bv = ov; bi = oi; }
            }
            if (tid < 8) {                  // 16B tagged record, 2x8B bypass;
                u64* pp = (u64*)(pq + (size_t)(t * 8 + tid) * NBS + blk);
                union { float f[2]; u64 u; } lo;
                lo.f[0] = s; lo.f[1] = bv;
                __hip_atomic_store(pp, lo.u, __ATOMIC_RELAXED, AGENT);
                u64 hi = (u64)(unsigned)bi | ((u64)(unsigned)(t + 1) << 32);
                // RELEASE orders the {sum,max} half before the tagged half.
                __hip_atomic_store(pp + 1, hi, __ATOMIC_RELEASE, AGENT);
            }
        }
        // NO barB: phase C synchronizes directly on the tagged pq records.

        // ------- phase C: dataflow reduce (poll own records) ---------------
        if (wv < 8) {
            const vfloat4* pqt = pq + (size_t)(t * 8 + wv) * NBS;
            float s = 0.f, bv = -1.f; int bi = 0x7fffffff;
#pragma unroll
            for (int c = 0; c < 4; c++) {
                int idx = lane + 64 * c;
                if (idx < NB) {
                    const u64* pp = (const u64*)(pqt + idx);
                    u64 hi = __hip_atomic_load(pp + 1, __ATOMIC_RELAXED, AGENT);
                    while ((unsigned)(hi >> 32) != (unsigned)(t + 1)) {
                        __builtin_amdgcn_s_sleep(1);
                        hi = __hip_atomic_load(pp + 1, __ATOMIC_RELAXED, AGENT);
                    }
                    union { u64 u; float f[2]; } lo;   // payload ordered by
                    lo.u = __hip_atomic_load(pp, __ATOMIC_RELAXED, AGENT);
                    s += lo.f[0];                      // producer's RELEASE
                    float ov = lo.f[1];
                    int   oi = (int)(unsigned)(hi & 0xFFFFFFFFu);
                    if (ov > bv || (ov == bv && oi < bi)) { bv = ov; bi = oi; }
                }
            }
            for (int m = 1; m < 64; m <<= 1) {
                s += __shfl_xor(s, m, 64);
                float ov = __shfl_xor(bv, m, 64);
                int   oi = __shfl_xor(bi, m, 64);
                if (ov > bv || (ov == bv && oi < bi)) { bv = ov; bi = oi; }
            }
            if (lane == 0) { s_S[wv] = s; s_Xn[wv] = bi; }
        }
        __syncthreads();
        {   // out write: FULL-LINE NT vfloat4 stores. Row slice = 256B aligned.
            float* out_t = out + (size_t)t * BB * V;
            if (tid < 128) {
                int row = tid >> 4;         // 0..7
                int c4  = (tid & 15) << 2;  // 0,4,...,60
                int xr = s_X[row];
                bool dn = (xr == 0) || (xr == 2);
                float inv = 1.f / s_S[row];
                int vbase = blk * CPB + c4;
                vfloat4 o4;
                o4.x = dn ? ((vbase + 0 == 0) ? 1.f : 0.f) : s_e[row * 65 + c4 + 0] * inv;
                o4.y = dn ? ((vbase + 1 == 0) ? 1.f : 0.f) : s_e[row * 65 + c4 + 1] * inv;
                o4.z = dn ? ((vbase + 2 == 0) ? 1.f : 0.f) : s_e[row * 65 + c4 + 2] * inv;
                o4.w = dn ? ((vbase + 3 == 0) ? 1.f : 0.f) : s_e[row * 65 + c4 + 3] * inv;
                __builtin_nontemporal_store(o4,
                    (vfloat4*)(out_t + (size_t)row * V + vbase));
            }
        }
        __syncthreads();
        if (tid < 8) {
            int xo = s_X[tid];
            s_X[tid] = ((xo == 0) || (xo == 2)) ? 0 : s_Xn[tid];
        }
        __syncthreads();
    }
}

extern "C" void kernel_launch(void* const* d_in, const int* in_sizes, int n_in,
                              void* d_out, int out_size, void* d_ws, size_t ws_size,
                              hipStream_t stream) {
    (void)in_sizes; (void)n_in; (void)out_size; (void)ws_size;
    const float* hidden    = (const float*)d_in[0];
    const float* embedding = (const float*)d_in[1];
    const float* w_ih      = (const float*)d_in[2];
    const float* w_hh      = (const float*)d_in[3];
    const float* b_ih      = (const float*)d_in[4];
    const float* b_hh      = (const float*)d_in[5];
    const float* w_out     = (const float*)d_in[6];
    const float* b_out     = (const float*)d_in[7];
    float* out = (float*)d_out;

    float* ws      = (float*)d_ws;
    float* hbuf    = ws;                             // (T+1)*BBH floats
    vfloat4* pq    = (vfloat4*)(hbuf + (size_t)(T + 1) * BBH);  // T*8*NBS x16B
    int*   cnt     = (int*)(pq + (size_t)T * 8 * NBS);          // CNT_LINES*16

    hipFuncSetAttribute((const void*)kmain,
        hipFuncAttributeMaxDynamicSharedMemorySize,
        (int)SMEM_BYTES);

    kinit<<<16, 256, 0, stream>>>(hidden, hbuf, cnt, pq);
    kmain<<<NB, TPB, SMEM_BYTES, stream>>>(embedding, w_ih, w_hh, b_ih, b_hh,
                                           w_out, b_out, hbuf, pq,
                                           cnt, out);
}

// Round 12
// 544.869 us; speedup vs baseline: 1.1892x; 1.1892x over previous
//
#include <hip/hip_runtime.h>

#define V 16000
#define E 256
#define H 512
#define HP 516     // padded LDS h row stride (4-float pad: bank groups 4r)
#define BB 8       // batch rows
#define T 12       // lenseq
#define NB 250     // persistent blocks: 250*64 == 16000 exactly (1 block/CU)
#define NBS 256    // pq stride (padded)
#define TPB 1024   // 16 waves/block
#define CPB 64     // vocab cols per block: 64*4B = 256B row slice, LINE-ALIGNED
#define BBH (BB * H)
#define AGENT __HIP_MEMORY_SCOPE_AGENT

typedef float vfloat4 __attribute__((ext_vector_type(4)));
typedef unsigned long long u64;

// Greedy degeneracy verified (R3). Persistent kernel since R4. w_out in LDS
// since R9. Established: (i) WRITE_SIZE amplification = red herring. (ii)
// R14/R18 tree-barrier + bypass-atomic data path is THE structure: every
// deviation regressed (R15 flat -65us, R16 fused+acquire -690us, R17
// plain-stores -30us, R19 relay+cached -33us, R20 dataflow-sync -81us).
// R18 op-shaping (coalesced 8B ops, packed pq, producer-only bar1) = best,
// 483us. R21 (this round): extend the R18-winning mechanism to its limit --
// 16B bypass ops via inline asm global_load/store_dwordx4 sc0 sc1 (same
// cache-bypass bits the compiler emits for agent atomics; no 16B atomic
// exists). h-stage 2x8B -> 1x16B; h-store 32x8B -> 16x16B; pq = one 16B
// record {sum,max,idx,_}; phase C = 4x16B loads issued back-to-back then one
// vmcnt(0) (keeps MLP). Halves bypass transactions/step 1.6M -> 0.8M.

// LDS layout (floats)
constexpr int W_FL   = CPB * 512;            // 32768  swizzled w slice (128KB)
constexpr int SH_OFF = W_FL;                 // s_h   [8][516]
constexpr int SP_OFF = SH_OFF + BB * HP;     // s_part 64*48 (A) / s_e [8][65] (B/C)
constexpr int RS_OFF = SP_OFF + 64 * 48;     // s_rsum [16][8] (+ phase-A h gather)
constexpr int RV_OFF = RS_OFF + 128;         // s_rval
constexpr int RI_OFF = RV_OFF + 128;         // s_ridx (int)
constexpr int SS_OFF = RI_OFF + 128;         // s_S   [8]
constexpr int XN_OFF = SS_OFF + 8;           // s_Xn  [8] (int)
constexpr int X_OFF  = XN_OFF + 8;           // s_X   [8] (int)
constexpr int SMEM_FL = X_OFF + 8;
constexpr size_t SMEM_BYTES = (size_t)SMEM_FL * 4;   // 161,504 B < 160 KiB

// cnt line map (16 ints per line):
//   lines 0..62 : bar2 leaf counters (62x4 + 2 = 250 arrivals)
//   line  63    : epochA word (h-ready publish)
//   lines 64..79: bar1 leaf counters (16 x 4 = 64 producer arrivals)
//   line  80    : epochB word (logits-ready publish)
constexpr int CNT_LINES = 84;

__device__ __forceinline__ float dot4(float4 a, float4 b) {
    return a.x * b.x + a.y * b.y + a.z * b.z + a.w * b.w;
}

// 16B cache-bypassing load/store (sc0 sc1 = device-scope coherent, same bits
// the compiler emits for agent-scope atomic ld/st; bypasses stale L2).
__device__ __forceinline__ vfloat4 ld16_bypass(const float* p) {
    vfloat4 v;
    asm volatile("global_load_dwordx4 %0, %1, off sc0 sc1\n\t"
                 "s_waitcnt vmcnt(0)"
                 : "=v"(v) : "v"(p) : "memory");
    return v;
}
__device__ __forceinline__ void st16_bypass(float* p, vfloat4 v) {
    asm volatile("global_store_dwordx4 %0, %1, off sc0 sc1"
                 :: "v"(p), "v"(v) : "memory");
}

__global__ __launch_bounds__(256) void kinit(const float* __restrict__ hidden,
                                             float* __restrict__ hbuf,
                                             int* __restrict__ cnt) {
    int idx = blockIdx.x * 256 + threadIdx.x;
    if (idx < BBH) hbuf[idx] = hidden[idx];
    if (idx < CNT_LINES * 16) cnt[idx] = 0;
}

// bar1 (R18 verbatim): producer-only arrivals (blocks 0..63 on 16 leaf
// lines) -> block0 publishes epochA -> everyone polls ONE word RELAXED.
__device__ __forceinline__ void barA(int* __restrict__ cnt, int ep) {
    __syncthreads();
    if (blockIdx.x < 64 && threadIdx.x == 0)
        __hip_atomic_fetch_add(&cnt[(64 + (blockIdx.x >> 2)) * 16], 1,
                               __ATOMIC_RELEASE, AGENT);
    if (blockIdx.x == 0) {
        if (threadIdx.x < 16) {
            while (__hip_atomic_load(&cnt[(64 + threadIdx.x) * 16],
                                     __ATOMIC_RELAXED, AGENT) < 4 * ep)
                __builtin_amdgcn_s_sleep(1);
        }
        __syncthreads();
        if (threadIdx.x == 0)
            __hip_atomic_store(&cnt[63 * 16], ep, __ATOMIC_RELAXED, AGENT);
    } else {
        if (threadIdx.x == 0) {
            while (__hip_atomic_load(&cnt[63 * 16], __ATOMIC_RELAXED, AGENT) < ep)
                __builtin_amdgcn_s_sleep(1);
        }
    }
    __builtin_amdgcn_fence(__ATOMIC_ACQUIRE, "workgroup");
    __syncthreads();
}

// bar2 (R18 verbatim): full-grid tree (63 leaves; leaf 62 has 2 blocks).
__device__ __forceinline__ void barB(int* __restrict__ cnt, int ep) {
    __syncthreads();
    if (threadIdx.x == 0) {
        int g = blockIdx.x >> 2;
        __hip_atomic_fetch_add(&cnt[g * 16], 1, __ATOMIC_RELEASE, AGENT);
    }
    if (blockIdx.x == 0) {
        if (threadIdx.x < 63) {
            int expct = (threadIdx.x == 62) ? 2 : 4;   // 62*4 + 2 = 250
            while (__hip_atomic_load(&cnt[threadIdx.x * 16],
                                     __ATOMIC_RELAXED, AGENT) < expct * ep)
                __builtin_amdgcn_s_sleep(1);
        }
        __syncthreads();
        if (threadIdx.x == 0)
            __hip_atomic_store(&cnt[80 * 16], ep, __ATOMIC_RELAXED, AGENT);
    } else {
        if (threadIdx.x == 0) {
            while (__hip_atomic_load(&cnt[80 * 16], __ATOMIC_RELAXED, AGENT) < ep)
                __builtin_amdgcn_s_sleep(1);
        }
    }
    __builtin_amdgcn_fence(__ATOMIC_ACQUIRE, "workgroup");
    __syncthreads();
}

__global__ __launch_bounds__(TPB, 4) void kmain(
    const float* __restrict__ emb_tab,
    const float* __restrict__ w_ih,
    const float* __restrict__ w_hh,
    const float* __restrict__ b_ih,
    const float* __restrict__ b_hh,
    const float* __restrict__ w_out,
    const float* __restrict__ b_out,
    float* __restrict__ hbuf,   // [T+1][BB*H] rotated h buffers
    vfloat4* __restrict__ pq,   // [T][8][NBS] {sum,max,idxbits,_}
    int* __restrict__ cnt,
    float* __restrict__ out)
{
    extern __shared__ float smem[];
    float* w_lds  = smem;
    float* s_h    = smem + SH_OFF;
    float* s_part = smem + SP_OFF;
    float* s_e    = smem + SP_OFF;          // alias: phase-B/C e buffer [8][65]
    float* s_rsum = smem + RS_OFF;
    float* s_rval = smem + RV_OFF;
    int*   s_ridx = (int*)(smem + RI_OFF);
    float* s_S    = smem + SS_OFF;
    int*   s_Xn   = (int*)(smem + XN_OFF);
    int*   s_X    = (int*)(smem + X_OFF);

    const int blk = blockIdx.x, tid = threadIdx.x;

    // ---- stage this block's w_out slice into LDS, swizzled, ONCE ----------
    // layout: w_lds[col*512 + (k ^ ((col&7)<<2) ^ (((k>>5)&7)<<2))]
    for (int i = tid; i < CPB * 128; i += TPB) {
        int col = i >> 7;
        int q4  = (i & 127) << 2;
        int vv  = blk * CPB + col;          // always < V (250*64 == 16000)
        float4 w4 = *(const float4*)(w_out + (size_t)vv * H + q4);
        int sw = q4 ^ ((col & 7) << 2) ^ (((q4 >> 5) & 7) << 2);
        *(float4*)(w_lds + col * 512 + sw) = w4;
    }
    if (tid < BB) s_X[tid] = 1;             // SOS
    __syncthreads();

    // ---- phase-B lane mapping: rh=bits0-1, kq=bits2-5 (16 K-chunks of 32)
    // wave: rowhalf=bit0, col-slot cs=bits1-4; per pass p: col = p*8 + cs
    const int lane = tid & 63;
    const int wv   = tid >> 6;              // 0..15
    const int rh   = lane & 3;
    const int kq   = (lane >> 2) & 15;      // K chunk (32 floats)
    const int rowhalf = wv & 1;
    const int cs   = wv >> 1;               // 0..7
    const int r    = rowhalf * 4 + rh;      // 0..7
    const int xw   = (cs ^ (kq & 7)) << 2;  // w swizzle for this (col-slot,kq)
    const int hswz = (kq & 7) << 2;         // h swizzle for this kq

    // b_out is step-invariant: hoist the 8 per-pass values into VGPRs once
    float bo[8];
#pragma unroll
    for (int p = 0; p < 8; p++) bo[p] = b_out[blk * CPB + p * 8 + cs];

    for (int t = 0; t < T; t++) {
        const float* h_cur = hbuf + (size_t)t * BBH;        // rotated
        float*       h_nxt = hbuf + (size_t)(t + 1) * BBH;  // write-once

        // ---------------- phase A: GRU cell (blocks 0..63) ----------------
        if (blk < 64) {                     // stage h_cur (one 16B bypass load)
            int hr = tid >> 7, k4 = (tid & 127) << 2;
            vfloat4 hv = ld16_bypass(h_cur + hr * H + k4);
            *(vfloat4*)(s_h + hr * HP + k4) = hv;
        }
        __syncthreads();
        if (blk < 64 && tid < 512) {
            const int jl = tid >> 6;        // 0..7
            const int ar = (tid >> 3) & 7;  // row
            const int kq8 = tid & 7;        // K split 8
            const int j  = blk * 8 + jl;
            const int pair = jl * 8 + ar;
            float gir = 0.f, giz = 0.f, gin = 0.f, ghr = 0.f, ghz = 0.f, ghn = 0.f;
            {
                const float* erow = emb_tab + (size_t)s_X[ar] * E;
                const float* w0 = w_ih + (size_t)j * E;
                const float* w1 = w0 + (size_t)H * E;
                const float* w2 = w1 + (size_t)H * E;
                const int k0 = kq8 * (E / 8);
                for (int k = 0; k < E / 8; k += 4) {
                    float4 ev = *(const float4*)(erow + k0 + k);
                    gir += dot4(*(const float4*)(w0 + k0 + k), ev);
                    giz += dot4(*(const float4*)(w1 + k0 + k), ev);
                    gin += dot4(*(const float4*)(w2 + k0 + k), ev);
                }
            }
            {
                const float* hrow = s_h + ar * HP;
                const float* w0 = w_hh + (size_t)j * H;
                const float* w1 = w0 + (size_t)H * H;
                const float* w2 = w1 + (size_t)H * H;
                const int k0 = kq8 * (H / 8);
                for (int k = 0; k < H / 8; k += 4) {
                    float4 hv = *(const float4*)(hrow + k0 + k);
                    ghr += dot4(*(const float4*)(w0 + k0 + k), hv);
                    ghz += dot4(*(const float4*)(w1 + k0 + k), hv);
                    ghn += dot4(*(const float4*)(w2 + k0 + k), hv);
                }
            }
            float* sp = s_part + pair * 48;
            sp[0 * 8 + kq8] = gir; sp[1 * 8 + kq8] = giz; sp[2 * 8 + kq8] = gin;
            sp[3 * 8 + kq8] = ghr; sp[4 * 8 + kq8] = ghz; sp[5 * 8 + kq8] = ghn;
        }
        __syncthreads();
        if (blk < 64 && tid < 512 && (tid & 7) == 0) {
            const int pair = (tid >> 6) * 8 + ((tid >> 3) & 7);
            const int jl = pair >> 3, ar = pair & 7;
            const int j  = blk * 8 + jl;
            const float* sp2 = s_part + pair * 48;
            float G[6];
#pragma unroll
            for (int gg = 0; gg < 6; gg++) {
                float s = 0.f;
#pragma unroll
                for (int q = 0; q < 8; q++) s += sp2[gg * 8 + q];
                G[gg] = s;
            }
            float ir  = G[0] + b_ih[j],         hr_ = G[3] + b_hh[j];
            float iz  = G[1] + b_ih[H + j],     hz  = G[4] + b_hh[H + j];
            float inn = G[2] + b_ih[2 * H + j], hn  = G[5] + b_hh[2 * H + j];
            float rg = 1.f / (1.f + __expf(-(ir + hr_)));
            float zg = 1.f / (1.f + __expf(-(iz + hz)));
            float ng = tanhf(inn + rg * hn);
            float ho = s_h[ar * HP + j];
            int xr = s_X[ar];
            bool dn = (xr == 0) || (xr == 2);
            float hv = dn ? ho : ((1.f - zg) * ng + zg * ho);
            s_rsum[ar * 8 + jl] = hv;       // gather for packed store
        }
        __syncthreads();
        if (blk < 64 && tid < 16) {         // 16 coalesced 16B bypass stores
            int ar = tid >> 1, q4 = (tid & 1) << 2;
            vfloat4 pk;
            pk.x = s_rsum[ar * 8 + q4];
            pk.y = s_rsum[ar * 8 + q4 + 1];
            pk.z = s_rsum[ar * 8 + q4 + 2];
            pk.w = s_rsum[ar * 8 + q4 + 3];
            st16_bypass(h_nxt + (size_t)ar * H + blk * 8 + q4, pk);
        }
        barA(cnt, t + 1);

        // -------- phase B: logits from LDS-resident w ----------------------
        {   // stage h_nxt, kq-swizzled (one 16B bypass load)
            int hr = tid >> 7, k4 = (tid & 127) << 2;
            vfloat4 hv = ld16_bypass(h_nxt + hr * H + k4);
            int sw = k4 ^ (((k4 >> 5) & 7) << 2);
            *(vfloat4*)(s_h + hr * HP + sw) = hv;
        }
        __syncthreads();
        {
            // h chunk -> 32 VGPRs, read ONCE per step
            float4 hreg[8];
            const float* hb = s_h + r * HP + kq * 32;
#pragma unroll
            for (int i = 0; i < 8; i++)
                hreg[i] = *(const float4*)(hb + ((4 * i) ^ hswz));

            float s_acc = 0.f, bv = -1.f; int bi = 0x7fffffff;
#pragma unroll
            for (int p = 0; p < 8; p++) {
                const int col = p * 8 + cs;
                const int vv  = blk * CPB + col;
                const float* wb = w_lds + col * 512 + kq * 32;
                float acc = 0.f;
#pragma unroll
                for (int i = 0; i < 8; i++) {
                    float4 w4 = *(const float4*)(wb + ((4 * i) ^ xw));
                    acc += dot4(w4, hreg[i]);
                }
                // full-K sum across the 16 kq lanes (bits 2-5); butterfly is
                // commutative-add -> bitwise identical on every lane
                acc += __shfl_xor(acc, 4, 64);
                acc += __shfl_xor(acc, 8, 64);
                acc += __shfl_xor(acc, 16, 64);
                acc += __shfl_xor(acc, 32, 64);
                float ee = __expf(acc + bo[p]);
                if (kq == 0) s_e[r * 65 + col] = ee;  // stash for phase-C write
                s_acc += ee;
                if (ee > bv) { bv = ee; bi = vv; }  // earlier pass = smaller v
            }
            if (kq == 0) {                  // designated: real per-r results
                s_rsum[wv * 8 + r] = s_acc;
                s_rval[wv * 8 + r] = bv;
                s_ridx[wv * 8 + r] = bi;
            } else if (kq == 1) {           // neutral fill for other row-half
                int ro = (1 - rowhalf) * 4 + rh;
                s_rsum[wv * 8 + ro] = 0.f;
                s_rval[wv * 8 + ro] = -1.f;
                s_ridx[wv * 8 + ro] = 0x7fffffff;
            }
        }
        __syncthreads();
        if (tid < 64) {                     // reduce 16 waves -> per-row, store
            float s  = s_rsum[tid] + s_rsum[tid + 64];
            float av = s_rval[tid], bv2 = s_rval[tid + 64];
            int   ai = s_ridx[tid], bi2 = s_ridx[tid + 64];
            float bv = av; int bi = ai;
            if (bv2 > bv || (bv2 == bv && bi2 < bi)) { bv = bv2; bi = bi2; }
#pragma unroll
            for (int m = 8; m <= 32; m <<= 1) {
                s += __shfl_xor(s, m, 64);
                float ov = __shfl_xor(bv, m, 64);
                int   oi = __shfl_xor(bi, m, 64);
                if (ov > bv || (ov == bv && oi < bi)) { bv = ov; bi = oi; }
            }
            if (tid < 8) {                  // ONE 16B bypass record
                vfloat4 q;
                q.x = s; q.y = bv; q.z = __int_as_float(bi); q.w = 0.f;
                st16_bypass((float*)(pq + (size_t)(t * 8 + tid) * NBS + blk), q);
            }
        }
        barB(cnt, t + 1);

        // ------- phase C: redundant reduce (4x16B bypass, pipelined) -------
        if (wv < 8) {
            const float* pqt = (const float*)(pq + (size_t)(t * 8 + wv) * NBS);
            const bool ok3 = (lane + 192) < NB;
            const float* p0 = pqt + (size_t)(lane)       * 4;
            const float* p1 = pqt + (size_t)(lane + 64)  * 4;
            const float* p2 = pqt + (size_t)(lane + 128) * 4;
            const float* p3 = pqt + (size_t)(ok3 ? lane + 192 : 0) * 4;
            vfloat4 q0, q1, q2, q3;
            asm volatile(
                "global_load_dwordx4 %0, %4, off sc0 sc1\n\t"
                "global_load_dwordx4 %1, %5, off sc0 sc1\n\t"
                "global_load_dwordx4 %2, %6, off sc0 sc1\n\t"
                "global_load_dwordx4 %3, %7, off sc0 sc1\n\t"
                "s_waitcnt vmcnt(0)"
                : "=&v"(q0), "=&v"(q1), "=&v"(q2), "=&v"(q3)
                : "v"(p0), "v"(p1), "v"(p2), "v"(p3)
                : "memory");
            float s = q0.x + q1.x + q2.x + (ok3 ? q3.x : 0.f);
            float bv = q0.y; int bi = (int)__float_as_uint(q0.z);
            {
                float ov = q1.y; int oi = (int)__float_as_uint(q1.z);
                if (ov > bv || (ov == bv && oi < bi)) { bv = ov; bi = oi; }
            }
            {
                float ov = q2.y; int oi = (int)__float_as_uint(q2.z);
                if (ov > bv || (ov == bv && oi < bi)) { bv = ov; bi = oi; }
            }
            if (ok3) {
                float ov = q3.y; int oi = (int)__float_as_uint(q3.z);
                if (ov > bv || (ov == bv && oi < bi)) { bv = ov; bi = oi; }
            }
            for (int m = 1; m < 64; m <<= 1) {
                s += __shfl_xor(s, m, 64);
                float ov = __shfl_xor(bv, m, 64);
                int   oi = __shfl_xor(bi, m, 64);
                if (ov > bv || (ov == bv && oi < bi)) { bv = ov; bi = oi; }
            }
            if (lane == 0) { s_S[wv] = s; s_Xn[wv] = bi; }
        }
        __syncthreads();
        {   // out write: FULL-LINE NT vfloat4 stores. Row slice = 256B aligned.
            float* out_t = out + (size_t)t * BB * V;
            if (tid < 128) {
                int row = tid >> 4;         // 0..7
                int c4  = (tid & 15) << 2;  // 0,4,...,60
                int xr = s_X[row];
                bool dn = (xr == 0) || (xr == 2);
                float inv = 1.f / s_S[row];
                int vbase = blk * CPB + c4;
                vfloat4 o4;
                o4.x = dn ? ((vbase + 0 == 0) ? 1.f : 0.f) : s_e[row * 65 + c4 + 0] * inv;
                o4.y = dn ? ((vbase + 1 == 0) ? 1.f : 0.f) : s_e[row * 65 + c4 + 1] * inv;
                o4.z = dn ? ((vbase + 2 == 0) ? 1.f : 0.f) : s_e[row * 65 + c4 + 2] * inv;
                o4.w = dn ? ((vbase + 3 == 0) ? 1.f : 0.f) : s_e[row * 65 + c4 + 3] * inv;
                __builtin_nontemporal_store(o4,
                    (vfloat4*)(out_t + (size_t)row * V + vbase));
            }
        }
        __syncthreads();
        if (tid < 8) {
            int xo = s_X[tid];
            s_X[tid] = ((xo == 0) || (xo == 2)) ? 0 : s_Xn[tid];
        }
        __syncthreads();
    }
}

extern "C" void kernel_launch(void* const* d_in, const int* in_sizes, int n_in,
                              void* d_out, int out_size, void* d_ws, size_t ws_size,
                              hipStream_t stream) {
    (void)in_sizes; (void)n_in; (void)out_size; (void)ws_size;
    const float* hidden    = (const float*)d_in[0];
    const float* embedding = (const float*)d_in[1];
    const float* w_ih      = (const float*)d_in[2];
    const float* w_hh      = (const float*)d_in[3];
    const float* b_ih      = (const float*)d_in[4];
    const float* b_hh      = (const float*)d_in[5];
    const float* w_out     = (const float*)d_in[6];
    const float* b_out     = (const float*)d_in[7];
    float* out = (float*)d_out;

    float* ws      = (float*)d_ws;
    float* hbuf    = ws;                             // (T+1)*BBH floats
    vfloat4* pq    = (vfloat4*)(hbuf + (size_t)(T + 1) * BBH);  // T*8*NBS x16B
    int*   cnt     = (int*)(pq + (size_t)T * 8 * NBS);          // CNT_LINES*16

    hipFuncSetAttribute((const void*)kmain,
        hipFuncAttributeMaxDynamicSharedMemorySize,
        (int)SMEM_BYTES);

    kinit<<<16, 256, 0, stream>>>(hidden, hbuf, cnt);
    kmain<<<NB, TPB, SMEM_BYTES, stream>>>(embedding, w_ih, w_hh, b_ih, b_hh,
                                           w_out, b_out, hbuf, pq,
                                           cnt, out);
}